// Round 3
// baseline (3978.884 us; speedup 1.0000x reference)
//
#include <hip/hip_runtime.h>
#include <math.h>

// ---------------- problem constants ----------------
#define S 256           // tokens (B=1)
#define D 512
#define P 4096
#define TOPK 8
#define NPAIR (S*TOPK)  // 2048
#define HMAX 2560

// ---------------- ws layout (float elements) ----------------
#define OFF_H1     0          // 256*256
#define OFF_H2     65536      // 256*128
#define OFF_SCORES 98304      // 256*4096
#define OFF_TOPV   1146880    // 2048
#define OFF_TOPI   1148928    // 2048 (int)
#define OFF_CNT    1150976    // 64 (int): [0..15] pre, [16..31] mlp, [32..47] post
#define OFF_LP     1151040    // 16*2048 int
#define OFF_LM     1183808
#define OFF_LQ     1216576
#define OFF_PRE    1249344    // 2048*512
#define OFF_HBUF   2297920    // 2048*2560
#define OFF_MLPO   7540800    // 2048*512
#define OFF_POSTL  8589376    // 2048*512
#define OFF_FREQ   9637952    // 4096
#define OFF_NIT    9642048    // 4 ints
#define OFF_QPRE   9642052    // 512 int4
#define OFF_QM1    9644100    // 2048 int4
#define OFF_QM2    9652292    // 512 int4
#define OFF_QPOST  9654340    // 512 int4

// d_out layout: [0,131072) output, [131072] glbl_loss, [131073, +1048576) pw

__device__ __forceinline__ float geluf(float x) {
    return 0.5f * x * (1.0f + erff(x * 0.70710678118654752440f));
}

__device__ __forceinline__ void async_copy16(float* lds, const float* g) {
    // global -> LDS direct, 16B per lane; LDS dest = wave-uniform base + lane*16
    __builtin_amdgcn_global_load_lds(
        (const __attribute__((address_space(1))) unsigned int*)g,
        (__attribute__((address_space(3))) unsigned int*)lds, 16, 0, 0);
}

__device__ __forceinline__ float blockReduceSum(float v, float* red, int tid) {
    __syncthreads();
    #pragma unroll
    for (int o = 32; o; o >>= 1) v += __shfl_down(v, o);
    if ((tid & 63) == 0) red[tid >> 6] = v;
    __syncthreads();
    return red[0] + red[1] + red[2] + red[3];
}

__device__ __forceinline__ float blockReduceMax(float v, float* red, int tid) {
    __syncthreads();
    #pragma unroll
    for (int o = 32; o; o >>= 1) v = fmaxf(v, __shfl_down(v, o));
    if ((tid & 63) == 0) red[tid >> 6] = v;
    __syncthreads();
    return fmaxf(fmaxf(red[0], red[1]), fmaxf(red[2], red[3]));
}

// ---------------- work-queue tiled GEMM ----------------
// Tile 64x64, K-step 32, 256 threads (4 waves), double-buffered LDS.
// A staged COALESCED: thread t reads row (t>>3), cols (t&7)*4..+3 (8 lanes =
// 128B contiguous per row), transposed into As[k][m] (pitch 68).
// Queue mode: items (e, m0, n0); rows via lists[e][r] (amode 1: row>>3 for A).
// Dense mode (queue==null): e=0, item = blockIdx over (M/64)x(denseNB) grid.
// act: 0 none, 1 gelu, 2 relu, 3 per-expert parity (even->gelu, odd->relu)
__global__ __launch_bounds__(256, 4) void gemm_tile(
    const float* __restrict__ A, int lda, int amode,
    const int* __restrict__ lists, const int* __restrict__ cnt,
    const int4* __restrict__ queue, const int* __restrict__ nItemsPtr, int stageIdx,
    int denseNB, int denseM,
    const float* __restrict__ W, long long wStride, int ldw,
    const float* __restrict__ bias, int biasStride,
    float* __restrict__ C, int ldc, int K, int hetK, int act)
{
    __shared__ float As[2][32][68];   // [k][m] transposed, pitch 68 (float4-aligned reads)
    __shared__ float Bs[2][32][64];   // [k][n] pitch 64 exact (global_load_lds linear)
    __shared__ int rAs[64];
    __shared__ int rC[64];

    int t = threadIdx.x;
    int wid = t >> 6;
    int lane = t & 63;
    int tr4 = (t >> 4) << 2;   // output row group (0..60)
    int tc4 = (t & 15) << 2;   // output col group (0..60)
    int rLo = t >> 3;          // A-stage row (0..31), +32 for second half
    int c4  = (t & 7) << 2;    // A-stage col group (0..28)

    int nWork = queue ? nItemsPtr[stageIdx] : (denseNB * ((denseM + 63) >> 6));

    for (int w = blockIdx.x; w < nWork; w += gridDim.x) {
        int e, m0, n0, Me;
        if (queue) {
            int4 it = queue[w];
            e = it.x; m0 = it.y; n0 = it.z;
            Me = cnt[e];
        } else {
            e = 0; m0 = (w / denseNB) * 64; n0 = (w % denseNB) * 64; Me = denseM;
        }
        int Ke = hetK ? (512 * (2 + (e >> 2))) : K;
        const float* We = W + (long long)e * wStride + n0;
        const int* le = lists ? (lists + (size_t)e * NPAIR) : nullptr;

        __syncthreads();   // previous item fully done with LDS / rAs / rC
        if (t < 64) {
            int r = m0 + t;
            int ar, cr;
            if (le) {
                int rr = (r < Me) ? r : (Me - 1);
                int pair = le[rr];
                ar = amode ? (pair >> 3) : pair;
                cr = (r < Me) ? pair : -1;
            } else { ar = r; cr = r; }
            rAs[t] = ar; rC[t] = cr;
        }
        __syncthreads();

        // coalesced A pointers: row rLo and rLo+32, cols c4..c4+3 (+k0)
        const float* aLo = A + (size_t)rAs[rLo] * lda + c4;
        const float* aHi = A + (size_t)rAs[rLo + 32] * lda + c4;
        const float* bBase = We + (size_t)(wid * 8 + (lane >> 4)) * ldw + ((lane & 15) << 2);
        float* bDst0 = &Bs[0][wid * 8][0];
        float* bDst1 = &Bs[1][wid * 8][0];

        float acc[4][4] = {};
        float4 av0, av1;

        // prologue: stage tile 0 into buf 0
        av0 = *(const float4*)(aLo);
        av1 = *(const float4*)(aHi);
        async_copy16(bDst0, bBase);
        async_copy16(bDst0 + 256, bBase + (size_t)4 * ldw);
        #pragma unroll
        for (int j = 0; j < 4; j++) As[0][c4 + j][rLo]      = ((const float*)&av0)[j];
        #pragma unroll
        for (int j = 0; j < 4; j++) As[0][c4 + j][rLo + 32] = ((const float*)&av1)[j];
        __syncthreads();

        int nk = Ke >> 5;
        int buf = 0;
        for (int ks = 0; ks < nk; ks++) {
            bool more = (ks + 1) < nk;
            if (more) {
                int k0 = (ks + 1) << 5;
                av0 = *(const float4*)(aLo + k0);
                av1 = *(const float4*)(aHi + k0);
                const float* g = bBase + (size_t)k0 * ldw;
                float* bd = buf ? bDst0 : bDst1;
                async_copy16(bd, g);
                async_copy16(bd + 256, g + (size_t)4 * ldw);
            }
            // compute on buf
            #pragma unroll
            for (int kk = 0; kk < 32; kk++) {
                float4 a = *(const float4*)&As[buf][kk][tr4];
                float4 b = *(const float4*)&Bs[buf][kk][tc4];
                acc[0][0] += a.x * b.x; acc[0][1] += a.x * b.y; acc[0][2] += a.x * b.z; acc[0][3] += a.x * b.w;
                acc[1][0] += a.y * b.x; acc[1][1] += a.y * b.y; acc[1][2] += a.y * b.z; acc[1][3] += a.y * b.w;
                acc[2][0] += a.z * b.x; acc[2][1] += a.z * b.y; acc[2][2] += a.z * b.z; acc[2][3] += a.z * b.w;
                acc[3][0] += a.w * b.x; acc[3][1] += a.w * b.y; acc[3][2] += a.w * b.z; acc[3][3] += a.w * b.w;
            }
            if (more) {
                int nb = buf ^ 1;
                #pragma unroll
                for (int j = 0; j < 4; j++) As[nb][c4 + j][rLo]      = ((const float*)&av0)[j];
                #pragma unroll
                for (int j = 0; j < 4; j++) As[nb][c4 + j][rLo + 32] = ((const float*)&av1)[j];
            }
            __syncthreads();
            buf ^= 1;
        }

        // epilogue: bias + act + store
        {
            const float* be = bias + (size_t)e * biasStride + n0 + tc4;
            float4 b4 = *(const float4*)be;
            int ae = (act == 3) ? ((e & 1) ? 2 : 1) : act;
            #pragma unroll
            for (int i = 0; i < 4; i++) {
                int cr = rC[tr4 + i];
                if (cr < 0) continue;
                float v0 = acc[i][0] + b4.x;
                float v1 = acc[i][1] + b4.y;
                float v2 = acc[i][2] + b4.z;
                float v3 = acc[i][3] + b4.w;
                if (ae == 1) { v0 = geluf(v0); v1 = geluf(v1); v2 = geluf(v2); v3 = geluf(v3); }
                else if (ae == 2) { v0 = fmaxf(v0, 0.f); v1 = fmaxf(v1, 0.f); v2 = fmaxf(v2, 0.f); v3 = fmaxf(v3, 0.f); }
                float4 v = make_float4(v0, v1, v2, v3);
                *(float4*)(C + (size_t)cr * ldc + n0 + tc4) = v;
            }
        }
    }
}

// ---------------- softmax + top-8 + pw + freq atomic ----------------
__global__ __launch_bounds__(256) void softmax_topk_kernel(
    const float* __restrict__ scores, const float* __restrict__ temp,
    float* __restrict__ freq, float* __restrict__ topv, int* __restrict__ topi,
    float* __restrict__ pw)
{
    __shared__ float s[P];
    __shared__ float red[8];
    __shared__ float lv[256];
    __shared__ int   li[256];
    __shared__ float tvS[TOPK];
    __shared__ int   tiS[TOPK];

    int t = blockIdx.x, tid = threadIdx.x;
    const float* srow = scores + (size_t)t * P;

    float loc[16];
    #pragma unroll
    for (int j = 0; j < 16; j++) { loc[j] = srow[tid + 256 * j]; }

    float m = -1e30f;
    #pragma unroll
    for (int j = 0; j < 16; j++) m = fmaxf(m, loc[j]);
    m = blockReduceMax(m, red, tid);

    float invT = 1.0f / temp[0];
    float p1[16], pT[16];
    float s1 = 0.f, sT = 0.f;
    #pragma unroll
    for (int j = 0; j < 16; j++) {
        float d = loc[j] - m;
        p1[j] = expf(d);        s1 += p1[j];
        pT[j] = expf(d * invT); sT += pT[j];
    }
    s1 = blockReduceSum(s1, red, tid);
    sT = blockReduceSum(sT, red, tid);

    float scale1 = (1.f / s1) * (1.f / (float)S);
    float* pwrow = pw + (size_t)t * P;
    #pragma unroll
    for (int j = 0; j < 16; j++) {
        int i = tid + 256 * j;
        atomicAdd(&freq[i], p1[j] * scale1);  // softmax(scores) col-mean accum
        s[i] = pT[j];                          // unnormalized softmax(scores/temp)
        pwrow[i] = 0.f;
    }
    __syncthreads();

    for (int it = 0; it < TOPK; it++) {
        float bv = -1e30f; int bi = -1;
        #pragma unroll
        for (int j = 0; j < 16; j++) {
            int i = tid + 256 * j;
            float v = s[i];
            if (v > bv) { bv = v; bi = i; }
        }
        lv[tid] = bv; li[tid] = bi;
        __syncthreads();
        for (int st = 128; st; st >>= 1) {
            if (tid < st) {
                float ov = lv[tid + st]; int oi = li[tid + st];
                if (ov > lv[tid] || (ov == lv[tid] && oi < li[tid])) { lv[tid] = ov; li[tid] = oi; }
            }
            __syncthreads();
        }
        if (tid == 0) { tvS[it] = lv[0]; tiS[it] = li[0]; s[li[0]] = -1e30f; }
        __syncthreads();
    }

    if (tid == 0) {
        float iZT = 1.f / sT;
        float tvn[TOPK]; float ssum = 0.f;
        #pragma unroll
        for (int it = 0; it < TOPK; it++) { tvn[it] = tvS[it] * iZT; ssum += tvn[it]; }
        float inv = 1.f / (ssum + 1e-8f);
        #pragma unroll
        for (int it = 0; it < TOPK; it++) {
            int pair = t * TOPK + it;
            topv[pair] = tvn[it];
            topi[pair] = tiS[it];
            pwrow[tiS[it]] = tvn[it] * inv;
        }
    }
}

__global__ __launch_bounds__(256) void glbl_kernel(const float* __restrict__ freq, float* __restrict__ outLoss) {
    __shared__ float red[8];
    int tid = threadIdx.x;
    float sum = 0.f;
    #pragma unroll
    for (int j = 0; j < 16; j++) sum += freq[tid + 256 * j];
    float tot = blockReduceSum(sum, red, tid);
    float mean = tot * (1.f / (float)P);
    float q = 0.f;
    #pragma unroll
    for (int j = 0; j < 16; j++) { float d = freq[tid + 256 * j] - mean; q += d * d; }
    float sq = blockReduceSum(q, red, tid);
    if (tid == 0) outLoss[0] = (float)P * (sq / (float)(P - 1));
}

__global__ void zero_misc_kernel(int* cnt, float* freq) {
    int t = threadIdx.x;
    if (t < 64) cnt[t] = 0;
    for (int i = t; i < P; i += 256) freq[i] = 0.f;
}

__global__ void build_lists_kernel(const int* __restrict__ topi, int* cnt,
                                   int* lp, int* lm, int* lq) {
    int pair = blockIdx.x * 256 + threadIdx.x;
    if (pair >= NPAIR) return;
    int idx = topi[pair];
    int pre = idx >> 8, rem = idx & 255, ml = rem >> 4, po = rem & 15;
    int pos;
    pos = atomicAdd(&cnt[pre], 1);      lp[pre * NPAIR + pos] = pair;
    pos = atomicAdd(&cnt[16 + ml], 1);  lm[ml * NPAIR + pos] = pair;
    pos = atomicAdd(&cnt[32 + po], 1);  lq[po * NPAIR + pos] = pair;
}

// enumerate GEMM tiles per stage into queues
__global__ void build_queue_kernel(const int* __restrict__ cnt,
                                   int4* qpre, int4* qm1, int4* qm2, int4* qpost,
                                   int* nItems) {
    __shared__ int ccount[64];
    __shared__ int coff[64];
    int t = threadIdx.x;
    int s = t >> 4, e = t & 15;
    if (t < 64) {
        int base = (s == 0) ? 0 : (s == 3) ? 32 : 16;
        int me = cnt[base + e];
        int nm = (me + 63) >> 6;
        int nb = (s == 1) ? (8 * (2 + (e >> 2))) : 8;
        ccount[t] = nm * nb;
    }
    __syncthreads();
    if (t == 0) {
        for (int ss = 0; ss < 4; ss++) {
            int run = 0;
            for (int i = 0; i < 16; i++) { coff[ss * 16 + i] = run; run += ccount[ss * 16 + i]; }
            nItems[ss] = run;
        }
    }
    __syncthreads();
    if (t < 64) {
        int base = (s == 0) ? 0 : (s == 3) ? 32 : 16;
        int me = cnt[base + e];
        int nm = (me + 63) >> 6;
        int nb = (s == 1) ? (8 * (2 + (e >> 2))) : 8;
        int4* q = (s == 0) ? qpre : (s == 1) ? qm1 : (s == 2) ? qm2 : qpost;
        int off = coff[t];
        for (int mb = 0; mb < nm; mb++)
            for (int nbk = 0; nbk < nb; nbk++)
                q[off++] = make_int4(e, mb * 64, nbk * 64, 0);
    }
}

// per-pair LayerNorm + activation (pre experts), in place on preOut
__global__ __launch_bounds__(256) void pre_lnact_kernel(
    float* __restrict__ preOut, const int* __restrict__ topi,
    const float* __restrict__ g, const float* __restrict__ b)
{
    __shared__ float red[8];
    int pair = blockIdx.x, tid = threadIdx.x;
    int e = topi[pair] >> 8;
    float* row = preOut + (size_t)pair * D;
    float v0 = row[tid], v1 = row[tid + 256];
    float sm = blockReduceSum(v0 + v1, red, tid) * (1.f / (float)D);
    float d0 = v0 - sm, d1 = v1 - sm;
    float vv = blockReduceSum(d0 * d0 + d1 * d1, red, tid) * (1.f / (float)D);
    float rs = rsqrtf(vv + 1e-5f);
    v0 = d0 * rs * g[e * D + tid]       + b[e * D + tid];
    v1 = d1 * rs * g[e * D + tid + 256] + b[e * D + tid + 256];
    int a = e % 3;
    if (a == 0)      { v0 = geluf(v0);      v1 = geluf(v1); }
    else if (a == 1) { v0 = fmaxf(v0, 0.f); v1 = fmaxf(v1, 0.f); }
    else             { v0 = tanhf(v0);      v1 = tanhf(v1); }
    row[tid] = v0; row[tid + 256] = v1;
}

// final: post-LN (even experts) + weighted sum over slots
__global__ __launch_bounds__(256) void combine_kernel(
    const float* __restrict__ postLin, const float* __restrict__ topv,
    const int* __restrict__ topi, const float* __restrict__ g,
    const float* __restrict__ b, float* __restrict__ out)
{
    __shared__ float red[8];
    int t = blockIdx.x, tid = threadIdx.x;
    float a0 = 0.f, a1 = 0.f;
    for (int sl = 0; sl < TOPK; sl++) {
        int pair = t * TOPK + sl;
        int e = topi[pair] & 15;
        float tv = topv[pair];
        const float* row = postLin + (size_t)pair * D;
        float v0 = row[tid], v1 = row[tid + 256];
        if ((e & 1) == 0) {
            float sm = blockReduceSum(v0 + v1, red, tid) * (1.f / (float)D);
            float d0 = v0 - sm, d1 = v1 - sm;
            float vv = blockReduceSum(d0 * d0 + d1 * d1, red, tid) * (1.f / (float)D);
            float rs = rsqrtf(vv + 1e-5f);
            v0 = d0 * rs * g[e * D + tid]       + b[e * D + tid];
            v1 = d1 * rs * g[e * D + tid + 256] + b[e * D + tid + 256];
        }
        a0 += tv * v0; a1 += tv * v1;
    }
    out[(size_t)t * D + tid] = a0;
    out[(size_t)t * D + tid + 256] = a1;
}

// ---------------- host entry ----------------
extern "C" void kernel_launch(void* const* d_in, const int* in_sizes, int n_in,
                              void* d_out, int out_size, void* d_ws, size_t ws_size,
                              hipStream_t stream) {
    const float* x    = (const float*)d_in[0];
    const float* Wr1  = (const float*)d_in[1];
    const float* br1  = (const float*)d_in[2];
    const float* Wr2  = (const float*)d_in[3];
    const float* br2  = (const float*)d_in[4];
    const float* Wr3  = (const float*)d_in[5];
    const float* br3  = (const float*)d_in[6];
    const float* temp = (const float*)d_in[7];
    const float* Wpre = (const float*)d_in[8];
    const float* bpre = (const float*)d_in[9];
    const float* gpre = (const float*)d_in[10];
    const float* bpre_ln = (const float*)d_in[11];
    const float* W1   = (const float*)d_in[12];
    const float* b1   = (const float*)d_in[13];
    const float* W2   = (const float*)d_in[14];
    const float* b2   = (const float*)d_in[15];
    const float* Wpost = (const float*)d_in[16];
    const float* bpost = (const float*)d_in[17];
    const float* gpost = (const float*)d_in[18];
    const float* bpost_ln = (const float*)d_in[19];

    float* ws = (float*)d_ws;
    float* h1      = ws + OFF_H1;
    float* h2      = ws + OFF_H2;
    float* scores  = ws + OFF_SCORES;
    float* topv    = ws + OFF_TOPV;
    int*   topi    = (int*)(ws + OFF_TOPI);
    int*   cnt     = (int*)(ws + OFF_CNT);
    int*   lp      = (int*)(ws + OFF_LP);
    int*   lm      = (int*)(ws + OFF_LM);
    int*   lq      = (int*)(ws + OFF_LQ);
    float* preOut  = ws + OFF_PRE;
    float* Hbuf    = ws + OFF_HBUF;
    float* mlpOut  = ws + OFF_MLPO;
    float* postLin = ws + OFF_POSTL;
    float* freq    = ws + OFF_FREQ;
    int*   nit     = (int*)(ws + OFF_NIT);
    int4*  qpre    = (int4*)(ws + OFF_QPRE);
    int4*  qm1     = (int4*)(ws + OFF_QM1);
    int4*  qm2     = (int4*)(ws + OFF_QM2);
    int4*  qpost   = (int4*)(ws + OFF_QPOST);

    float* out     = (float*)d_out;
    float* outLoss = out + S * D;
    float* pw      = out + S * D + 1;

    hipLaunchKernelGGL(zero_misc_kernel, dim3(1), dim3(256), 0, stream, cnt, freq);

    // ---- router (dense mode) ----
    // r1: h1 = gelu(x @ Wr1 + br1)  [256,256] K=512
    hipLaunchKernelGGL(gemm_tile, dim3(16), dim3(256), 0, stream,
        x, D, 0, (const int*)nullptr, (const int*)nullptr,
        (const int4*)nullptr, (const int*)nullptr, 0, 4, S,
        Wr1, 0LL, 256, br1, 0, h1, 256, 512, 0, 1);
    // r2: h2 = gelu(h1 @ Wr2 + br2) [256,128] K=256
    hipLaunchKernelGGL(gemm_tile, dim3(8), dim3(256), 0, stream,
        h1, 256, 0, (const int*)nullptr, (const int*)nullptr,
        (const int4*)nullptr, (const int*)nullptr, 0, 2, S,
        Wr2, 0LL, 128, br2, 0, h2, 128, 256, 0, 1);
    // r3: scores = h2 @ Wr3 + br3   [256,4096] K=128
    hipLaunchKernelGGL(gemm_tile, dim3(256), dim3(256), 0, stream,
        h2, 128, 0, (const int*)nullptr, (const int*)nullptr,
        (const int4*)nullptr, (const int*)nullptr, 0, 64, S,
        Wr3, 0LL, P, br3, 0, scores, P, 128, 0, 0);

    hipLaunchKernelGGL(softmax_topk_kernel, dim3(S), dim3(256), 0, stream,
        scores, temp, freq, topv, topi, pw);
    hipLaunchKernelGGL(glbl_kernel, dim3(1), dim3(256), 0, stream, freq, outLoss);

    hipLaunchKernelGGL(build_lists_kernel, dim3(8), dim3(256), 0, stream, topi, cnt, lp, lm, lq);
    hipLaunchKernelGGL(build_queue_kernel, dim3(1), dim3(256), 0, stream, cnt, qpre, qm1, qm2, qpost, nit);

    // ---- pre experts: preOut[pair] = x[token] @ Wpre[e] + bpre[e] ----
    hipLaunchKernelGGL(gemm_tile, dim3(512), dim3(256), 0, stream,
        x, D, 1, lp, cnt, qpre, nit, 0, 0, 0,
        Wpre, (long long)D * D, D, bpre, D, preOut, D, 512, 0, 0);
    hipLaunchKernelGGL(pre_lnact_kernel, dim3(NPAIR), dim3(256), 0, stream,
        preOut, topi, gpre, bpre_ln);

    // ---- mlp stage 1: H = act(preOut @ W1[e][:, :h] + b1[e]) ----
    hipLaunchKernelGGL(gemm_tile, dim3(1024), dim3(256), 0, stream,
        preOut, D, 0, lm, cnt + 16, qm1, nit, 1, 0, 0,
        W1, (long long)D * HMAX, HMAX, b1, HMAX, Hbuf, HMAX, 512, 0, 3);
    // ---- mlp stage 2: mlpOut = H[:, :h] @ W2[e][:h, :] + b2[e] ----
    hipLaunchKernelGGL(gemm_tile, dim3(512), dim3(256), 0, stream,
        Hbuf, HMAX, 0, lm, cnt + 16, qm2, nit, 2, 0, 0,
        W2, (long long)HMAX * D, D, b2, D, mlpOut, D, 0, 1, 0);

    // ---- post experts: postLin = mlpOut @ Wpost[e] + bpost[e] ----
    hipLaunchKernelGGL(gemm_tile, dim3(512), dim3(256), 0, stream,
        mlpOut, D, 0, lq, cnt + 32, qpost, nit, 3, 0, 0,
        Wpost, (long long)D * D, D, bpost, D, postLin, D, 512, 0, 0);

    hipLaunchKernelGGL(combine_kernel, dim3(S), dim3(256), 0, stream,
        postLin, topv, topi, gpost, bpost_ln, out);
}

// Round 5
// 723.290 us; speedup vs baseline: 5.5011x; 5.5011x over previous
//
#include <hip/hip_runtime.h>
#include <math.h>

// ---------------- problem constants ----------------
#define S 256           // tokens (B=1)
#define D 512
#define P 4096
#define TOPK 8
#define NPAIR (S*TOPK)  // 2048
#define HMAX 2560

// ---------------- ws layout (float elements) ----------------
#define OFF_H1     0          // 256*256
#define OFF_H2     65536      // 256*128
#define OFF_SCORES 98304      // 256*4096
#define OFF_TOPV   1146880    // 2048
#define OFF_TOPI   1148928    // 2048 (int)
#define OFF_CNT    1150976    // 64 (int): [0..15] pre, [16..31] mlp, [32..47] post
#define OFF_LP     1151040    // 16*2048 int
#define OFF_LM     1183808
#define OFF_LQ     1216576
#define OFF_PRE    1249344    // 2048*512
#define OFF_HBUF   2297920    // 2048*2560
#define OFF_MLPO   7540800    // 2048*512
#define OFF_POSTL  8589376    // 2048*512
#define OFF_FREQ   9637952    // 4096
#define OFF_NIT    9642048    // 4 ints
#define OFF_QPRE   9642052    // 512 int4
#define OFF_QM1    9644100    // 2048 int4
#define OFF_QM2    9652292    // 512 int4
#define OFF_QPOST  9654340    // 512 int4

// d_out layout: [0,131072) output, [131072] glbl_loss, [131073, +1048576) pw

__device__ __forceinline__ float geluf(float x) {
    return 0.5f * x * (1.0f + erff(x * 0.70710678118654752440f));
}

__device__ __forceinline__ void async_copy16(float* lds, const float* g) {
    // global -> LDS direct, 16B per lane; LDS dest = wave-uniform base + lane*16
    __builtin_amdgcn_global_load_lds(
        (const __attribute__((address_space(1))) unsigned int*)g,
        (__attribute__((address_space(3))) unsigned int*)lds, 16, 0, 0);
}

__device__ __forceinline__ float blockReduceSum(float v, float* red, int tid) {
    __syncthreads();
    #pragma unroll
    for (int o = 32; o; o >>= 1) v += __shfl_down(v, o);
    if ((tid & 63) == 0) red[tid >> 6] = v;
    __syncthreads();
    return red[0] + red[1] + red[2] + red[3];
}

__device__ __forceinline__ float blockReduceMax(float v, float* red, int tid) {
    __syncthreads();
    #pragma unroll
    for (int o = 32; o; o >>= 1) v = fmaxf(v, __shfl_down(v, o));
    if ((tid & 63) == 0) red[tid >> 6] = v;
    __syncthreads();
    return fmaxf(fmaxf(red[0], red[1]), fmaxf(red[2], red[3]));
}

// ---------------- work-queue tiled GEMM ----------------
// Tile 64x64, K-step 32, 256 threads (4 waves), double-buffered LDS.
// A staged COALESCED: thread t reads row (t>>3), cols (t&7)*4..+3 (8 lanes =
// 128B contiguous per row), transposed into As[k][m] (pitch 68).
// NOTE: no min-waves launch_bounds — forcing 4 blocks/CU spilled to scratch
// (r3: VGPR 64, 4 GB scratch traffic, 5x slower). Natural alloc ~160 VGPR.
// Queue mode: items (e, m0, n0); rows via lists[e][r] (amode 1: row>>3 for A).
// Dense mode (queue==null): e=0, item = blockIdx over (M/64)x(denseNB) grid.
// act: 0 none, 1 gelu, 2 relu, 3 per-expert parity (even->gelu, odd->relu)
__global__ __launch_bounds__(256) void gemm_tile(
    const float* __restrict__ A, int lda, int amode,
    const int* __restrict__ lists, const int* __restrict__ cnt,
    const int4* __restrict__ queue, const int* __restrict__ nItemsPtr, int stageIdx,
    int denseNB, int denseM,
    const float* __restrict__ W, long long wStride, int ldw,
    const float* __restrict__ bias, int biasStride,
    float* __restrict__ C, int ldc, int K, int hetK, int act)
{
    __shared__ float As[2][32][68];   // [k][m] transposed, pitch 68 (float4-aligned reads)
    __shared__ float Bs[2][32][64];   // [k][n] pitch 64 exact (global_load_lds linear)
    __shared__ int rAs[64];
    __shared__ int rC[64];

    int t = threadIdx.x;
    int wid = t >> 6;
    int lane = t & 63;
    int tr4 = (t >> 4) << 2;   // output row group (0..60)
    int tc4 = (t & 15) << 2;   // output col group (0..60)
    int rLo = t >> 3;          // A-stage row (0..31), +32 for second half
    int c4  = (t & 7) << 2;    // A-stage col group (0..28)

    int nWork = queue ? nItemsPtr[stageIdx] : (denseNB * ((denseM + 63) >> 6));

    for (int w = blockIdx.x; w < nWork; w += gridDim.x) {
        int e, m0, n0, Me;
        if (queue) {
            int4 it = queue[w];
            e = it.x; m0 = it.y; n0 = it.z;
            Me = cnt[e];
        } else {
            e = 0; m0 = (w / denseNB) * 64; n0 = (w % denseNB) * 64; Me = denseM;
        }
        int Ke = hetK ? (512 * (2 + (e >> 2))) : K;
        const float* We = W + (long long)e * wStride + n0;
        const int* le = lists ? (lists + (size_t)e * NPAIR) : nullptr;

        __syncthreads();   // previous item fully done with LDS / rAs / rC
        if (t < 64) {
            int r = m0 + t;
            int ar, cr;
            if (le) {
                int rr = (r < Me) ? r : (Me - 1);
                int pair = le[rr];
                ar = amode ? (pair >> 3) : pair;
                cr = (r < Me) ? pair : -1;
            } else { ar = r; cr = r; }
            rAs[t] = ar; rC[t] = cr;
        }
        __syncthreads();

        // coalesced A pointers: row rLo and rLo+32, cols c4..c4+3 (+k0)
        const float* aLo = A + (size_t)rAs[rLo] * lda + c4;
        const float* aHi = A + (size_t)rAs[rLo + 32] * lda + c4;
        const float* bBase = We + (size_t)(wid * 8 + (lane >> 4)) * ldw + ((lane & 15) << 2);
        float* bDst0 = &Bs[0][wid * 8][0];
        float* bDst1 = &Bs[1][wid * 8][0];

        float acc[4][4] = {};
        float4 av0, av1;

        // prologue: stage tile 0 into buf 0
        av0 = *(const float4*)(aLo);
        av1 = *(const float4*)(aHi);
        async_copy16(bDst0, bBase);
        async_copy16(bDst0 + 256, bBase + (size_t)4 * ldw);
        #pragma unroll
        for (int j = 0; j < 4; j++) As[0][c4 + j][rLo]      = ((const float*)&av0)[j];
        #pragma unroll
        for (int j = 0; j < 4; j++) As[0][c4 + j][rLo + 32] = ((const float*)&av1)[j];
        __syncthreads();

        int nk = Ke >> 5;
        int buf = 0;
        for (int ks = 0; ks < nk; ks++) {
            bool more = (ks + 1) < nk;
            if (more) {
                int k0 = (ks + 1) << 5;
                av0 = *(const float4*)(aLo + k0);
                av1 = *(const float4*)(aHi + k0);
                const float* g = bBase + (size_t)k0 * ldw;
                float* bd = buf ? bDst0 : bDst1;
                async_copy16(bd, g);
                async_copy16(bd + 256, g + (size_t)4 * ldw);
            }
            // compute on buf
            #pragma unroll
            for (int kk = 0; kk < 32; kk++) {
                float4 a = *(const float4*)&As[buf][kk][tr4];
                float4 b = *(const float4*)&Bs[buf][kk][tc4];
                acc[0][0] += a.x * b.x; acc[0][1] += a.x * b.y; acc[0][2] += a.x * b.z; acc[0][3] += a.x * b.w;
                acc[1][0] += a.y * b.x; acc[1][1] += a.y * b.y; acc[1][2] += a.y * b.z; acc[1][3] += a.y * b.w;
                acc[2][0] += a.z * b.x; acc[2][1] += a.z * b.y; acc[2][2] += a.z * b.z; acc[2][3] += a.z * b.w;
                acc[3][0] += a.w * b.x; acc[3][1] += a.w * b.y; acc[3][2] += a.w * b.z; acc[3][3] += a.w * b.w;
            }
            if (more) {
                int nb = buf ^ 1;
                #pragma unroll
                for (int j = 0; j < 4; j++) As[nb][c4 + j][rLo]      = ((const float*)&av0)[j];
                #pragma unroll
                for (int j = 0; j < 4; j++) As[nb][c4 + j][rLo + 32] = ((const float*)&av1)[j];
            }
            __syncthreads();
            buf ^= 1;
        }

        // epilogue: bias + act + store
        {
            const float* be = bias + (size_t)e * biasStride + n0 + tc4;
            float4 b4 = *(const float4*)be;
            int ae = (act == 3) ? ((e & 1) ? 2 : 1) : act;
            #pragma unroll
            for (int i = 0; i < 4; i++) {
                int cr = rC[tr4 + i];
                if (cr < 0) continue;
                float v0 = acc[i][0] + b4.x;
                float v1 = acc[i][1] + b4.y;
                float v2 = acc[i][2] + b4.z;
                float v3 = acc[i][3] + b4.w;
                if (ae == 1) { v0 = geluf(v0); v1 = geluf(v1); v2 = geluf(v2); v3 = geluf(v3); }
                else if (ae == 2) { v0 = fmaxf(v0, 0.f); v1 = fmaxf(v1, 0.f); v2 = fmaxf(v2, 0.f); v3 = fmaxf(v3, 0.f); }
                float4 v = make_float4(v0, v1, v2, v3);
                *(float4*)(C + (size_t)cr * ldc + n0 + tc4) = v;
            }
        }
    }
}

// ---------------- softmax + top-8 + pw + freq atomic ----------------
__global__ __launch_bounds__(256) void softmax_topk_kernel(
    const float* __restrict__ scores, const float* __restrict__ temp,
    float* __restrict__ freq, float* __restrict__ topv, int* __restrict__ topi,
    float* __restrict__ pw)
{
    __shared__ float s[P];
    __shared__ float red[8];
    __shared__ float lv[256];
    __shared__ int   li[256];
    __shared__ float tvS[TOPK];
    __shared__ int   tiS[TOPK];

    int t = blockIdx.x, tid = threadIdx.x;
    const float* srow = scores + (size_t)t * P;

    float loc[16];
    #pragma unroll
    for (int j = 0; j < 16; j++) { loc[j] = srow[tid + 256 * j]; }

    float m = -1e30f;
    #pragma unroll
    for (int j = 0; j < 16; j++) m = fmaxf(m, loc[j]);
    m = blockReduceMax(m, red, tid);

    float invT = 1.0f / temp[0];
    float p1[16], pT[16];
    float s1 = 0.f, sT = 0.f;
    #pragma unroll
    for (int j = 0; j < 16; j++) {
        float d = loc[j] - m;
        p1[j] = expf(d);        s1 += p1[j];
        pT[j] = expf(d * invT); sT += pT[j];
    }
    s1 = blockReduceSum(s1, red, tid);
    sT = blockReduceSum(sT, red, tid);

    float scale1 = (1.f / s1) * (1.f / (float)S);
    float* pwrow = pw + (size_t)t * P;
    #pragma unroll
    for (int j = 0; j < 16; j++) {
        int i = tid + 256 * j;
        atomicAdd(&freq[i], p1[j] * scale1);  // softmax(scores) col-mean accum
        s[i] = pT[j];                          // unnormalized softmax(scores/temp)
        pwrow[i] = 0.f;
    }
    __syncthreads();

    for (int it = 0; it < TOPK; it++) {
        float bv = -1e30f; int bi = -1;
        #pragma unroll
        for (int j = 0; j < 16; j++) {
            int i = tid + 256 * j;
            float v = s[i];
            if (v > bv) { bv = v; bi = i; }
        }
        lv[tid] = bv; li[tid] = bi;
        __syncthreads();
        for (int st = 128; st; st >>= 1) {
            if (tid < st) {
                float ov = lv[tid + st]; int oi = li[tid + st];
                if (ov > lv[tid] || (ov == lv[tid] && oi < li[tid])) { lv[tid] = ov; li[tid] = oi; }
            }
            __syncthreads();
        }
        if (tid == 0) { tvS[it] = lv[0]; tiS[it] = li[0]; s[li[0]] = -1e30f; }
        __syncthreads();
    }

    if (tid == 0) {
        float iZT = 1.f / sT;
        float tvn[TOPK]; float ssum = 0.f;
        #pragma unroll
        for (int it = 0; it < TOPK; it++) { tvn[it] = tvS[it] * iZT; ssum += tvn[it]; }
        float inv = 1.f / (ssum + 1e-8f);
        #pragma unroll
        for (int it = 0; it < TOPK; it++) {
            int pair = t * TOPK + it;
            topv[pair] = tvn[it];
            topi[pair] = tiS[it];
            pwrow[tiS[it]] = tvn[it] * inv;
        }
    }
}

__global__ __launch_bounds__(256) void glbl_kernel(const float* __restrict__ freq, float* __restrict__ outLoss) {
    __shared__ float red[8];
    int tid = threadIdx.x;
    float sum = 0.f;
    #pragma unroll
    for (int j = 0; j < 16; j++) sum += freq[tid + 256 * j];
    float tot = blockReduceSum(sum, red, tid);
    float mean = tot * (1.f / (float)P);
    float q = 0.f;
    #pragma unroll
    for (int j = 0; j < 16; j++) { float d = freq[tid + 256 * j] - mean; q += d * d; }
    float sq = blockReduceSum(q, red, tid);
    if (tid == 0) outLoss[0] = (float)P * (sq / (float)(P - 1));
}

__global__ void zero_misc_kernel(int* cnt, float* freq) {
    int t = threadIdx.x;
    if (t < 64) cnt[t] = 0;
    for (int i = t; i < P; i += 256) freq[i] = 0.f;
}

__global__ void build_lists_kernel(const int* __restrict__ topi, int* cnt,
                                   int* lp, int* lm, int* lq) {
    int pair = blockIdx.x * 256 + threadIdx.x;
    if (pair >= NPAIR) return;
    int idx = topi[pair];
    int pre = idx >> 8, rem = idx & 255, ml = rem >> 4, po = rem & 15;
    int pos;
    pos = atomicAdd(&cnt[pre], 1);      lp[pre * NPAIR + pos] = pair;
    pos = atomicAdd(&cnt[16 + ml], 1);  lm[ml * NPAIR + pos] = pair;
    pos = atomicAdd(&cnt[32 + po], 1);  lq[po * NPAIR + pos] = pair;
}

// enumerate GEMM tiles per stage into queues
__global__ void build_queue_kernel(const int* __restrict__ cnt,
                                   int4* qpre, int4* qm1, int4* qm2, int4* qpost,
                                   int* nItems) {
    __shared__ int ccount[64];
    __shared__ int coff[64];
    int t = threadIdx.x;
    int s = t >> 4, e = t & 15;
    if (t < 64) {
        int base = (s == 0) ? 0 : (s == 3) ? 32 : 16;
        int me = cnt[base + e];
        int nm = (me + 63) >> 6;
        int nb = (s == 1) ? (8 * (2 + (e >> 2))) : 8;
        ccount[t] = nm * nb;
    }
    __syncthreads();
    if (t == 0) {
        for (int ss = 0; ss < 4; ss++) {
            int run = 0;
            for (int i = 0; i < 16; i++) { coff[ss * 16 + i] = run; run += ccount[ss * 16 + i]; }
            nItems[ss] = run;
        }
    }
    __syncthreads();
    if (t < 64) {
        int base = (s == 0) ? 0 : (s == 3) ? 32 : 16;
        int me = cnt[base + e];
        int nm = (me + 63) >> 6;
        int nb = (s == 1) ? (8 * (2 + (e >> 2))) : 8;
        int4* q = (s == 0) ? qpre : (s == 1) ? qm1 : (s == 2) ? qm2 : qpost;
        int off = coff[t];
        for (int mb = 0; mb < nm; mb++)
            for (int nbk = 0; nbk < nb; nbk++)
                q[off++] = make_int4(e, mb * 64, nbk * 64, 0);
    }
}

// per-pair LayerNorm + activation (pre experts), in place on preOut
__global__ __launch_bounds__(256) void pre_lnact_kernel(
    float* __restrict__ preOut, const int* __restrict__ topi,
    const float* __restrict__ g, const float* __restrict__ b)
{
    __shared__ float red[8];
    int pair = blockIdx.x, tid = threadIdx.x;
    int e = topi[pair] >> 8;
    float* row = preOut + (size_t)pair * D;
    float v0 = row[tid], v1 = row[tid + 256];
    float sm = blockReduceSum(v0 + v1, red, tid) * (1.f / (float)D);
    float d0 = v0 - sm, d1 = v1 - sm;
    float vv = blockReduceSum(d0 * d0 + d1 * d1, red, tid) * (1.f / (float)D);
    float rs = rsqrtf(vv + 1e-5f);
    v0 = d0 * rs * g[e * D + tid]       + b[e * D + tid];
    v1 = d1 * rs * g[e * D + tid + 256] + b[e * D + tid + 256];
    int a = e % 3;
    if (a == 0)      { v0 = geluf(v0);      v1 = geluf(v1); }
    else if (a == 1) { v0 = fmaxf(v0, 0.f); v1 = fmaxf(v1, 0.f); }
    else             { v0 = tanhf(v0);      v1 = tanhf(v1); }
    row[tid] = v0; row[tid + 256] = v1;
}

// final: post-LN (even experts) + weighted sum over slots
__global__ __launch_bounds__(256) void combine_kernel(
    const float* __restrict__ postLin, const float* __restrict__ topv,
    const int* __restrict__ topi, const float* __restrict__ g,
    const float* __restrict__ b, float* __restrict__ out)
{
    __shared__ float red[8];
    int t = blockIdx.x, tid = threadIdx.x;
    float a0 = 0.f, a1 = 0.f;
    for (int sl = 0; sl < TOPK; sl++) {
        int pair = t * TOPK + sl;
        int e = topi[pair] & 15;
        float tv = topv[pair];
        const float* row = postLin + (size_t)pair * D;
        float v0 = row[tid], v1 = row[tid + 256];
        if ((e & 1) == 0) {
            float sm = blockReduceSum(v0 + v1, red, tid) * (1.f / (float)D);
            float d0 = v0 - sm, d1 = v1 - sm;
            float vv = blockReduceSum(d0 * d0 + d1 * d1, red, tid) * (1.f / (float)D);
            float rs = rsqrtf(vv + 1e-5f);
            v0 = d0 * rs * g[e * D + tid]       + b[e * D + tid];
            v1 = d1 * rs * g[e * D + tid + 256] + b[e * D + tid + 256];
        }
        a0 += tv * v0; a1 += tv * v1;
    }
    out[(size_t)t * D + tid] = a0;
    out[(size_t)t * D + tid + 256] = a1;
}

// ---------------- host entry ----------------
extern "C" void kernel_launch(void* const* d_in, const int* in_sizes, int n_in,
                              void* d_out, int out_size, void* d_ws, size_t ws_size,
                              hipStream_t stream) {
    const float* x    = (const float*)d_in[0];
    const float* Wr1  = (const float*)d_in[1];
    const float* br1  = (const float*)d_in[2];
    const float* Wr2  = (const float*)d_in[3];
    const float* br2  = (const float*)d_in[4];
    const float* Wr3  = (const float*)d_in[5];
    const float* br3  = (const float*)d_in[6];
    const float* temp = (const float*)d_in[7];
    const float* Wpre = (const float*)d_in[8];
    const float* bpre = (const float*)d_in[9];
    const float* gpre = (const float*)d_in[10];
    const float* bpre_ln = (const float*)d_in[11];
    const float* W1   = (const float*)d_in[12];
    const float* b1   = (const float*)d_in[13];
    const float* W2   = (const float*)d_in[14];
    const float* b2   = (const float*)d_in[15];
    const float* Wpost = (const float*)d_in[16];
    const float* bpost = (const float*)d_in[17];
    const float* gpost = (const float*)d_in[18];
    const float* bpost_ln = (const float*)d_in[19];

    float* ws = (float*)d_ws;
    float* h1      = ws + OFF_H1;
    float* h2      = ws + OFF_H2;
    float* scores  = ws + OFF_SCORES;
    float* topv    = ws + OFF_TOPV;
    int*   topi    = (int*)(ws + OFF_TOPI);
    int*   cnt     = (int*)(ws + OFF_CNT);
    int*   lp      = (int*)(ws + OFF_LP);
    int*   lm      = (int*)(ws + OFF_LM);
    int*   lq      = (int*)(ws + OFF_LQ);
    float* preOut  = ws + OFF_PRE;
    float* Hbuf    = ws + OFF_HBUF;
    float* mlpOut  = ws + OFF_MLPO;
    float* postLin = ws + OFF_POSTL;
    float* freq    = ws + OFF_FREQ;
    int*   nit     = (int*)(ws + OFF_NIT);
    int4*  qpre    = (int4*)(ws + OFF_QPRE);
    int4*  qm1     = (int4*)(ws + OFF_QM1);
    int4*  qm2     = (int4*)(ws + OFF_QM2);
    int4*  qpost   = (int4*)(ws + OFF_QPOST);

    float* out     = (float*)d_out;
    float* outLoss = out + S * D;
    float* pw      = out + S * D + 1;

    hipLaunchKernelGGL(zero_misc_kernel, dim3(1), dim3(256), 0, stream, cnt, freq);

    // ---- router (dense mode) ----
    // r1: h1 = gelu(x @ Wr1 + br1)  [256,256] K=512
    hipLaunchKernelGGL(gemm_tile, dim3(16), dim3(256), 0, stream,
        x, D, 0, (const int*)nullptr, (const int*)nullptr,
        (const int4*)nullptr, (const int*)nullptr, 0, 4, S,
        Wr1, 0LL, 256, br1, 0, h1, 256, 512, 0, 1);
    // r2: h2 = gelu(h1 @ Wr2 + br2) [256,128] K=256
    hipLaunchKernelGGL(gemm_tile, dim3(8), dim3(256), 0, stream,
        h1, 256, 0, (const int*)nullptr, (const int*)nullptr,
        (const int4*)nullptr, (const int*)nullptr, 0, 2, S,
        Wr2, 0LL, 128, br2, 0, h2, 128, 256, 0, 1);
    // r3: scores = h2 @ Wr3 + br3   [256,4096] K=128
    hipLaunchKernelGGL(gemm_tile, dim3(256), dim3(256), 0, stream,
        h2, 128, 0, (const int*)nullptr, (const int*)nullptr,
        (const int4*)nullptr, (const int*)nullptr, 0, 64, S,
        Wr3, 0LL, P, br3, 0, scores, P, 128, 0, 0);

    hipLaunchKernelGGL(softmax_topk_kernel, dim3(S), dim3(256), 0, stream,
        scores, temp, freq, topv, topi, pw);
    hipLaunchKernelGGL(glbl_kernel, dim3(1), dim3(256), 0, stream, freq, outLoss);

    hipLaunchKernelGGL(build_lists_kernel, dim3(8), dim3(256), 0, stream, topi, cnt, lp, lm, lq);
    hipLaunchKernelGGL(build_queue_kernel, dim3(1), dim3(256), 0, stream, cnt, qpre, qm1, qm2, qpost, nit);

    // ---- pre experts: preOut[pair] = x[token] @ Wpre[e] + bpre[e] ----
    hipLaunchKernelGGL(gemm_tile, dim3(512), dim3(256), 0, stream,
        x, D, 1, lp, cnt, qpre, nit, 0, 0, 0,
        Wpre, (long long)D * D, D, bpre, D, preOut, D, 512, 0, 0);
    hipLaunchKernelGGL(pre_lnact_kernel, dim3(NPAIR), dim3(256), 0, stream,
        preOut, topi, gpre, bpre_ln);

    // ---- mlp stage 1: H = act(preOut @ W1[e][:, :h] + b1[e]) ----
    hipLaunchKernelGGL(gemm_tile, dim3(1024), dim3(256), 0, stream,
        preOut, D, 0, lm, cnt + 16, qm1, nit, 1, 0, 0,
        W1, (long long)D * HMAX, HMAX, b1, HMAX, Hbuf, HMAX, 512, 0, 3);
    // ---- mlp stage 2: mlpOut = H[:, :h] @ W2[e][:h, :] + b2[e] ----
    hipLaunchKernelGGL(gemm_tile, dim3(512), dim3(256), 0, stream,
        Hbuf, HMAX, 0, lm, cnt + 16, qm2, nit, 2, 0, 0,
        W2, (long long)HMAX * D, D, b2, D, mlpOut, D, 0, 1, 0);

    // ---- post experts: postLin = mlpOut @ Wpost[e] + bpost[e] ----
    hipLaunchKernelGGL(gemm_tile, dim3(512), dim3(256), 0, stream,
        mlpOut, D, 0, lq, cnt + 32, qpost, nit, 3, 0, 0,
        Wpost, (long long)D * D, D, bpost, D, postLin, D, 512, 0, 0);

    hipLaunchKernelGGL(combine_kernel, dim3(S), dim3(256), 0, stream,
        postLin, topv, topi, gpost, bpost_ln, out);
}